// Round 24
// baseline (225.807 us; speedup 1.0000x reference)
//
#include <hip/hip_runtime.h>
#include <hip/hip_bf16.h>
#include <stdint.h>

typedef unsigned short u16;
typedef __attribute__((ext_vector_type(4))) float f32x4;
typedef __attribute__((ext_vector_type(8))) short bf16x8;
typedef __attribute__((ext_vector_type(4))) short bf16x4;
typedef __attribute__((ext_vector_type(4))) unsigned short u16x4;

static __device__ __forceinline__ u16 f2bf(float f) {
    union { float f; unsigned u; } v; v.f = f;
    unsigned r = v.u + 0x7fffu + ((v.u >> 16) & 1u);
    return (u16)(r >> 16);
}

// async global->LDS, 16B per lane; LDS dest = wave-uniform base + lane*16
static __device__ __forceinline__ void gload_lds16(const u16* g, u16* l) {
    __builtin_amdgcn_global_load_lds(
        (const __attribute__((address_space(1))) void*)(uintptr_t)g,
        (__attribute__((address_space(3))) void*)(uint32_t)(uintptr_t)l,
        16, 0, 0);
}

// ---------------- fused prologue: 6 weight transposes + LN1 in ONE launch -------------
// Blocks [0,12288): transpose out[n*K+k] = (bf16) W[k*N+n] per segment:
//   [0,3072): Wq/Wk/Wv (per-head 1024x64); [3072,4096): Wp; [4096,8192): W1;
//   [8192,12288): W2 (4096x1024).
// Blocks [12288,16384): LN1 row (id-12288) of x -> h (bf16).
__global__ __launch_bounds__(256) void prologue_fused(
    const float* __restrict__ Wq, const float* __restrict__ Wk,
    const float* __restrict__ Wv, const float* __restrict__ Wp,
    const float* __restrict__ W1, const float* __restrict__ W2,
    u16* __restrict__ wqkvT, u16* __restrict__ wpT,
    u16* __restrict__ w1T, u16* __restrict__ w2T,
    const float* __restrict__ x, const float* __restrict__ g,
    const float* __restrict__ be, u16* __restrict__ hout)
{
    __shared__ float tile[32][33];
    __shared__ float ps[4], pq[4];
    const int id = blockIdx.x;
    if (id >= 12288) {
        // ---- LN1 row ----
        const int row = id - 12288;
        const int t = threadIdx.x;
        const float4* xr = (const float4*)(x + (size_t)row * 1024);
        float4 v = xr[t];
        float s = v.x + v.y + v.z + v.w;
        float sq = v.x * v.x + v.y * v.y + v.z * v.z + v.w * v.w;
        #pragma unroll
        for (int o = 1; o < 64; o <<= 1) {
            s  += __shfl_xor(s, o);
            sq += __shfl_xor(sq, o);
        }
        if ((t & 63) == 0) { ps[t >> 6] = s; pq[t >> 6] = sq; }
        __syncthreads();
        float S = ps[0] + ps[1] + ps[2] + ps[3];
        float Q = pq[0] + pq[1] + pq[2] + pq[3];
        float mu = S * (1.0f / 1024.0f);
        float var = Q * (1.0f / 1024.0f) - mu * mu;
        float rs = rsqrtf(var + 1e-5f);
        const float4 g4  = ((const float4*)g)[t];
        const float4 be4 = ((const float4*)be)[t];
        u16x4 o4;
        o4[0] = f2bf((v.x - mu) * rs * g4.x + be4.x);
        o4[1] = f2bf((v.y - mu) * rs * g4.y + be4.y);
        o4[2] = f2bf((v.z - mu) * rs * g4.z + be4.z);
        o4[3] = f2bf((v.w - mu) * rs * g4.w + be4.w);
        *(u16x4*)(hout + (size_t)row * 1024 + t * 4) = o4;
        return;
    }
    // ---- weight transpose tile ----
    const float* W; u16* out; int K, N, nt, kt;
    if (id < 3072) {
        const int seg = id >> 10;            // 0:Wq 1:Wk 2:Wv
        const int r = id & 1023;
        const int z = r >> 6;                // head
        const int rem = r & 63;
        W = (seg == 0 ? Wq : (seg == 1 ? Wk : Wv)) + (size_t)z * 65536;
        out = wqkvT + seg * 1048576 + (size_t)z * 65536;
        K = 1024; N = 64;
        nt = (rem & 1) * 32; kt = (rem >> 1) * 32;
    } else if (id < 4096) {
        const int r = id - 3072;
        W = Wp; out = wpT; K = 1024; N = 1024;
        nt = (r & 31) * 32; kt = (r >> 5) * 32;
    } else if (id < 8192) {
        const int r = id - 4096;
        W = W1; out = w1T; K = 1024; N = 4096;
        nt = (r & 127) * 32; kt = (r >> 7) * 32;
    } else {
        const int r = id - 8192;
        W = W2; out = w2T; K = 4096; N = 1024;
        nt = (r & 31) * 32; kt = (r >> 5) * 32;
    }
    const int tx = threadIdx.x & 31, ty = threadIdx.x >> 5;
    #pragma unroll
    for (int i = ty; i < 32; i += 8)
        tile[i][tx] = W[(size_t)(kt + i) * N + nt + tx];
    __syncthreads();
    #pragma unroll
    for (int i = ty; i < 32; i += 8)
        out[(size_t)(nt + i) * K + kt + tx] = f2bf(tile[tx][i]);
}

// ---------------- layernorm: fp32 in -> bf16 out (D = 1024) ---------------
__global__ __launch_bounds__(256) void ln_kernel(
    const float* __restrict__ x, const float* __restrict__ g,
    const float* __restrict__ be, u16* __restrict__ out)
{
    int row = blockIdx.x;
    int t = threadIdx.x;
    const float4* xr = (const float4*)(x + (size_t)row * 1024);
    float4 v = xr[t];
    float s = v.x + v.y + v.z + v.w;
    float sq = v.x * v.x + v.y * v.y + v.z * v.z + v.w * v.w;
    #pragma unroll
    for (int o = 1; o < 64; o <<= 1) {
        s  += __shfl_xor(s, o);
        sq += __shfl_xor(sq, o);
    }
    __shared__ float ps[4], pq[4];
    if ((t & 63) == 0) { ps[t >> 6] = s; pq[t >> 6] = sq; }
    __syncthreads();
    float S = ps[0] + ps[1] + ps[2] + ps[3];
    float Q = pq[0] + pq[1] + pq[2] + pq[3];
    float mu = S * (1.0f / 1024.0f);
    float var = Q * (1.0f / 1024.0f) - mu * mu;
    float rs = rsqrtf(var + 1e-5f);
    const float4 g4  = ((const float4*)g)[t];
    const float4 be4 = ((const float4*)be)[t];
    u16x4 o4;
    o4[0] = f2bf((v.x - mu) * rs * g4.x + be4.x);
    o4[1] = f2bf((v.y - mu) * rs * g4.y + be4.y);
    o4[2] = f2bf((v.z - mu) * rs * g4.z + be4.z);
    o4[3] = f2bf((v.w - mu) * rs * g4.w + be4.w);
    *(u16x4*)(out + (size_t)row * 1024 + t * 4) = o4;
}

// ---------------- GEMM 128x128, BK=64, counted-vmcnt pipelined K-loop (r11) ----------
// XCD-banded 1D grid: XCD k owns M-strips [k*spx, (k+1)*spx), walks N-tiles fast.
template<int EPI>
__global__ __launch_bounds__(256) void gemm_bt(
    const u16* __restrict__ A, const u16* __restrict__ Bt,
    int M, int N, int K,
    const float* __restrict__ bias,
    void* __restrict__ Cout, u16* __restrict__ Kf, u16* __restrict__ Vf)
{
    __shared__ __align__(16) u16 SH[32768];   // 64 KB: 2 bufs x (A 16KB + B 16KB)
    const int bid = blockIdx.x;
    const int xcd = bid & 7, idx = bid >> 3;
    const int nmx = N >> 7;                    // N-tiles
    const int spx = (M >> 7) >> 3;             // M-strips per XCD
    const int tm = (xcd * spx + idx / nmx) * 128;
    const int tn = (idx % nmx) * 128;
    const int t = threadIdx.x;
    const int lane = t & 63, wave = t >> 6;
    const int wr = wave >> 1, wc = wave & 1;
    const int lq = lane & 15, lg = lane >> 4;
    f32x4 acc[4][4] = {};

    const int srow8 = lane >> 3;                       // 0..7
    const int skoff = ((lane & 7) ^ srow8) * 8;        // u16 offset within 64-wide k
    const u16* ag = A  + (size_t)(tm + wave * 32 + srow8) * K + skoff;
    const u16* bg = Bt + (size_t)(tn + wave * 32 + srow8) * K + skoff;

    auto STAGE = [&](int buf, int k0) {
        u16* ab = SH + buf * 16384 + wave * 2048;
        u16* bb = SH + buf * 16384 + 8192 + wave * 2048;
        #pragma unroll
        for (int j = 0; j < 4; ++j) {
            gload_lds16(ag + (size_t)(j * 8) * K + k0, ab + j * 512);
            gload_lds16(bg + (size_t)(j * 8) * K + k0, bb + j * 512);
        }
    };

    const int KT = K >> 6;
    STAGE(0, 0);
    STAGE(1, 64);
    asm volatile("s_waitcnt vmcnt(8)" ::: "memory");
    __builtin_amdgcn_sched_barrier(0);
    __builtin_amdgcn_s_barrier();

    for (int kt = 0; kt < KT; ++kt) {
        const int buf = kt & 1;
        const u16* abuf = SH + buf * 16384;
        const u16* bbuf = abuf + 8192;
        bf16x8 af[4][2], bfv[4][2];
        #pragma unroll
        for (int m = 0; m < 4; ++m) {
            const int row = wr * 64 + m * 16 + lq;
            #pragma unroll
            for (int kk = 0; kk < 2; ++kk) {
                const int slot = (kk * 4 + lg) ^ (row & 7);
                af[m][kk] = *(const bf16x8*)(abuf + row * 64 + slot * 8);
            }
        }
        #pragma unroll
        for (int n = 0; n < 4; ++n) {
            const int col = wc * 64 + n * 16 + lq;
            #pragma unroll
            for (int kk = 0; kk < 2; ++kk) {
                const int slot = (kk * 4 + lg) ^ (col & 7);
                bfv[n][kk] = *(const bf16x8*)(bbuf + col * 64 + slot * 8);
            }
        }
        asm volatile("s_waitcnt lgkmcnt(0)" ::: "memory");
        __builtin_amdgcn_sched_barrier(0);
        __builtin_amdgcn_s_barrier();

        const bool pre = (kt + 2 < KT);
        if (pre) STAGE(buf, (kt + 2) << 6);

        __builtin_amdgcn_s_setprio(1);
        #pragma unroll
        for (int m = 0; m < 4; ++m)
            #pragma unroll
            for (int n = 0; n < 4; ++n)
                #pragma unroll
                for (int kk = 0; kk < 2; ++kk)
                    acc[m][n] = __builtin_amdgcn_mfma_f32_16x16x32_bf16(
                        af[m][kk], bfv[n][kk], acc[m][n], 0, 0, 0);
        __builtin_amdgcn_s_setprio(0);

        if (kt + 1 < KT) {
            if (pre) asm volatile("s_waitcnt vmcnt(8)" ::: "memory");
            else     asm volatile("s_waitcnt vmcnt(0)" ::: "memory");
            __builtin_amdgcn_sched_barrier(0);
            __builtin_amdgcn_s_barrier();
        }
    }

    // ---------------- epilogue: stage into LDS, then coalesced dump ----------------
    if (EPI == 2 || (EPI == 3 && tn < 1024)) {
        __syncthreads();
        #pragma unroll
        for (int n = 0; n < 4; ++n) {
            const int cl = wc * 64 + n * 16 + lq;
            #pragma unroll
            for (int m = 0; m < 4; ++m) {
                const int rl = wr * 64 + m * 16 + lg * 4;
                #pragma unroll
                for (int r = 0; r < 4; ++r) {
                    float v = acc[m][n][r];
                    if (EPI == 2) {
                        float xx = v + bias[tn + cl];
                        v = 0.5f * xx * (1.0f + erff(xx * 0.70710678118654752f));
                    }
                    SH[(rl + r) * 136 + cl] = f2bf(v);
                }
            }
        }
        __syncthreads();
        const int row = t >> 1, half = t & 1;
        const int ncols = (EPI == 2) ? N : 1024;
        const uint4* srow4 = (const uint4*)(SH + row * 136 + half * 64);
        uint4* drow = (uint4*)((u16*)Cout + (size_t)(tm + row) * ncols + tn + half * 64);
        #pragma unroll
        for (int i = 0; i < 8; ++i)
            drow[i] = srow4[i];
    } else if (EPI == 3) {
        __syncthreads();
        const bool isK = (tn < 2048);
        #pragma unroll
        for (int n = 0; n < 4; ++n) {
            const int cl = wc * 64 + n * 16 + lq;
            const int d = cl & 63, hl = cl >> 6;
            #pragma unroll
            for (int m = 0; m < 4; ++m) {
                const int rl0 = wr * 64 + m * 16 + lg * 4;
                #pragma unroll
                for (int r = 0; r < 4; ++r) {
                    const int rl = rl0 + r;
                    const int p = rl & 63, kl = rl >> 6;
                    int off;
                    if (isK)
                        off = ((p >> 4) * 2 + (d >> 5)) * 512 + ((d >> 3) & 3) * 128
                            + (p & 15) * 8 + (d & 7);
                    else
                        off = ((p >> 4) * 4 + (d >> 4)) * 256 + ((p >> 2) & 3) * 64
                            + (d & 15) * 4 + (p & 3);
                    SH[(hl * 2 + kl) * 4096 + off] = f2bf(acc[m][n][r]);
                }
            }
        }
        __syncthreads();
        const int img = t >> 6, ln = t & 63;
        const int hl = img >> 1, kl = img & 1;
        const int hh = ((tn - (isK ? 1024 : 2048)) >> 6) + hl;
        const int bb = tm >> 11, pp = tm & 2047;
        u16* base = (isK ? Kf : Vf) + (size_t)(bb * 16 + hh) * 131072
                  + (size_t)((pp >> 6) + kl) * 4096;
        const u16* simg = SH + img * 4096;
        #pragma unroll
        for (int i = 0; i < 8; ++i)
            *(uint4*)(base + ln * 8 + i * 512) = *(const uint4*)(simg + ln * 8 + i * 512);
    }
}

// ---------------- GEMM 128x64, BK=64, counted-vmcnt pipeline, XCD-banded -------------
__global__ __launch_bounds__(256) void gemm_bt64(
    const u16* __restrict__ A, const u16* __restrict__ Bt,
    int M, int N, int K,
    const float* __restrict__ bias, const float* __restrict__ res,
    float* __restrict__ Cout)
{
    __shared__ __align__(16) u16 SH[24576];   // 48 KB
    const int bid = blockIdx.x;
    const int xcd = bid & 7, idx = bid >> 3;
    const int nmx = N >> 6;                    // N-tiles (64 wide)
    const int spx = (M >> 7) >> 3;             // M-strips per XCD
    const int tm = (xcd * spx + idx / nmx) * 128;
    const int tn = (idx % nmx) * 64;
    const int t = threadIdx.x;
    const int lane = t & 63, wave = t >> 6;
    const int wr = wave >> 1, wc = wave & 1;      // wave tile: 64 rows x 32 cols
    const int lq = lane & 15, lg = lane >> 4;
    f32x4 acc[4][2] = {};

    const int srow8 = lane >> 3;                       // 0..7
    const int skoff = ((lane & 7) ^ srow8) * 8;        // pre-swizzled source slot
    const u16* ag = A  + (size_t)(tm + wave * 32 + srow8) * K + skoff;
    const u16* bg = Bt + (size_t)(tn + wave * 16 + srow8) * K + skoff;

    auto STAGE = [&](int buf, int k0) {
        u16* ab = SH + buf * 12288 + wave * 2048;          // A: [128][64]
        u16* bb = SH + buf * 12288 + 8192 + wave * 1024;   // B: [64][64]
        #pragma unroll
        for (int j = 0; j < 4; ++j)
            gload_lds16(ag + (size_t)(j * 8) * K + k0, ab + j * 512);
        #pragma unroll
        for (int j = 0; j < 2; ++j)
            gload_lds16(bg + (size_t)(j * 8) * K + k0, bb + j * 512);
    };

    const int KT = K >> 6;
    STAGE(0, 0);
    STAGE(1, 64);
    asm volatile("s_waitcnt vmcnt(6)" ::: "memory");
    __builtin_amdgcn_sched_barrier(0);
    __builtin_amdgcn_s_barrier();

    for (int kt = 0; kt < KT; ++kt) {
        const int buf = kt & 1;
        const u16* abuf = SH + buf * 12288;
        const u16* bbuf = abuf + 8192;
        bf16x8 af[4][2], bfr[2][2];
        #pragma unroll
        for (int m = 0; m < 4; ++m) {
            const int row = wr * 64 + m * 16 + lq;
            #pragma unroll
            for (int kk = 0; kk < 2; ++kk) {
                const int slot = (kk * 4 + lg) ^ (row & 7);
                af[m][kk] = *(const bf16x8*)(abuf + row * 64 + slot * 8);
            }
        }
        #pragma unroll
        for (int n = 0; n < 2; ++n) {
            const int col = wc * 32 + n * 16 + lq;
            #pragma unroll
            for (int kk = 0; kk < 2; ++kk) {
                const int slot = (kk * 4 + lg) ^ (col & 7);
                bfr[n][kk] = *(const bf16x8*)(bbuf + col * 64 + slot * 8);
            }
        }
        asm volatile("s_waitcnt lgkmcnt(0)" ::: "memory");
        __builtin_amdgcn_sched_barrier(0);
        __builtin_amdgcn_s_barrier();

        const bool pre = (kt + 2 < KT);
        if (pre) STAGE(buf, (kt + 2) << 6);

        __builtin_amdgcn_s_setprio(1);
        #pragma unroll
        for (int m = 0; m < 4; ++m)
            #pragma unroll
            for (int n = 0; n < 2; ++n)
                #pragma unroll
                for (int kk = 0; kk < 2; ++kk)
                    acc[m][n] = __builtin_amdgcn_mfma_f32_16x16x32_bf16(
                        af[m][kk], bfr[n][kk], acc[m][n], 0, 0, 0);
        __builtin_amdgcn_s_setprio(0);

        if (kt + 1 < KT) {
            if (pre) asm volatile("s_waitcnt vmcnt(6)" ::: "memory");
            else     asm volatile("s_waitcnt vmcnt(0)" ::: "memory");
            __builtin_amdgcn_sched_barrier(0);
            __builtin_amdgcn_s_barrier();
        }
    }

    #pragma unroll
    for (int m = 0; m < 4; ++m)
        #pragma unroll
        for (int n = 0; n < 2; ++n) {
            const int col = tn + wc * 32 + n * 16 + lq;
            #pragma unroll
            for (int r = 0; r < 4; ++r) {
                const int row = tm + wr * 64 + m * 16 + lg * 4 + r;
                Cout[(size_t)row * N + col] = acc[m][n][r] + bias[col] + res[(size_t)row * N + col];
            }
        }
}

// ---------------- causal flash attention: 4 waves/block, LDS-staged K/V --------------
__global__ __launch_bounds__(256, 4) void attn_kernel(
    const u16* __restrict__ qb, const u16* __restrict__ Kf,
    const u16* __restrict__ Vf, u16* __restrict__ o)
{
    const int P = 2048;
    __shared__ __align__(16) u16 KB[2][4096];
    __shared__ __align__(16) u16 VB[2][4096];
    int blk = blockIdx.x;
    int qt = 31 - (blk >> 5);           // 64-row q tiles, heavy first (LPT)
    int bh = blk & 31;
    int h = bh & 15, b = bh >> 4;
    int w = threadIdx.x >> 6, lane = threadIdx.x & 63;
    int lq = lane & 15, lg = lane >> 4;
    int q0 = qt * 64 + w * 16;
    const u16* qptr = qb + (size_t)(b * P + q0 + lq) * 1024 + h * 64 + lg * 8;
    bf16x8 qf0 = *(const bf16x8*)qptr;
    bf16x8 qf1 = *(const bf16x8*)(qptr + 32);
    const u16* Kfb = Kf + (size_t)bh * 131072;
    const u16* Vfb = Vf + (size_t)bh * 131072;
    const float C2 = 0.03125f * 1.44269504f;     // D^-0.5 * log2(e)
    const int moff = w * 16 + lq;                // causal threshold within last block
    float m2 = -1e30f, l_run = 0.f;
    f32x4 accO[4] = {};
    const int nkvb = qt + 1;

    const int vsel = w >> 1, half = w & 1;
    auto STAGE = [&](int buf, int kvb) {
        const u16* src = (vsel ? Vfb : Kfb) + (size_t)kvb * 4096 + half * 2048 + lane * 8;
        u16* dst = (vsel ? &VB[buf][half * 2048] : &KB[buf][half * 2048]);
        #pragma unroll
        for (int i = 0; i < 4; ++i)
            gload_lds16(src + i * 512, dst + i * 512);
    };

    auto COMPUTE = [&](int buf, bool last) {
        const u16* kbase = KB[buf] + lane * 8;
        f32x4 st[4];
        #pragma unroll
        for (int ss = 0; ss < 4; ++ss) {
            bf16x8 kf0 = *(const bf16x8*)(kbase + ss * 1024);
            bf16x8 kf1 = *(const bf16x8*)(kbase + ss * 1024 + 512);
            f32x4 z = {0.f, 0.f, 0.f, 0.f};
            st[ss] = __builtin_amdgcn_mfma_f32_16x16x32_bf16(kf0, qf0, z, 0, 0, 0);
            st[ss] = __builtin_amdgcn_mfma_f32_16x16x32_bf16(kf1, qf1, st[ss], 0, 0, 0);
        }
        float rmax = -1e30f;
        #pragma unroll
        for (int ss = 0; ss < 4; ++ss)
            #pragma unroll
            for (int r = 0; r < 4; ++r) {
                float v = st[ss][r] * C2;
                if (last && (ss * 16 + lg * 4 + r > moff)) v = -1e30f;
                st[ss][r] = v;
                rmax = fmaxf(rmax, v);
            }
        rmax = fmaxf(rmax, __shfl_xor(rmax, 16));
        rmax = fmaxf(rmax, __shfl_xor(rmax, 32));
        if (__any(rmax > m2 + 11.5f)) {            // defer-max (T13)
            float m2n = fmaxf(m2, rmax);
            float alpha = exp2f(m2 - m2n);
            l_run *= alpha;
            #pragma unroll
            for (int r = 0; r < 4; ++r) {
                float ar = __shfl(alpha, lg * 4 + r);
                accO[0][r] *= ar; accO[1][r] *= ar; accO[2][r] *= ar; accO[3][r] *= ar;
            }
            m2 = m2n;
        }
        float psum = 0.f;
        bf16x4 pf[4];
        #pragma unroll
        for (int ss = 0; ss < 4; ++ss)
            #pragma unroll
            for (int r = 0; r < 4; ++r) {
                float pv = exp2f(st[ss][r] - m2);
                psum += pv;
                pf[ss][r] = (short)f2bf(pv);
            }
        psum += __shfl_xor(psum, 16);
        psum += __shfl_xor(psum, 32);
        l_run += psum;
        const u16* vbase = VB[buf] + lane * 4;
        #pragma unroll
        for (int ks = 0; ks < 4; ++ks)
            #pragma unroll
            for (int c = 0; c < 4; ++c) {
                bf16x4 vfr = *(const bf16x4*)(vbase + (ks * 4 + c) * 256);
                accO[c] = __builtin_amdgcn_mfma_f32_16x16x16bf16_1k(pf[ks], vfr, accO[c], 0, 0, 0);
            }
    };

    STAGE(0, 0);
    __syncthreads();
    int cur = 0;
    for (int kvb = 0; kvb < nkvb; ++kvb) {
        if (kvb + 1 < nkvb) STAGE(cur ^ 1, kvb + 1);
        COMPUTE(cur, kvb == nkvb - 1);
        __syncthreads();
        cur ^= 1;
    }

    #pragma unroll
    for (int r = 0; r < 4; ++r) {
        float l_r = __shfl(l_run, lg * 4 + r);
        float inv = 1.0f / l_r;
        size_t orow = (size_t)(b * P + q0 + lg * 4 + r) * 1024 + h * 64;
        #pragma unroll
        for (int c = 0; c < 4; ++c)
            o[orow + c * 16 + lq] = f2bf(accO[c][r] * inv);
    }
}

extern "C" void kernel_launch(void* const* d_in, const int* in_sizes, int n_in,
                              void* d_out, int out_size, void* d_ws, size_t ws_size,
                              hipStream_t stream)
{
    const float* x   = (const float*)d_in[0];
    const float* Wq  = (const float*)d_in[1];
    const float* Wk  = (const float*)d_in[2];
    const float* Wv  = (const float*)d_in[3];
    const float* Wp  = (const float*)d_in[4];
    const float* bp  = (const float*)d_in[5];
    const float* W1  = (const float*)d_in[6];
    const float* b1  = (const float*)d_in[7];
    const float* W2  = (const float*)d_in[8];
    const float* b2  = (const float*)d_in[9];
    const float* g1  = (const float*)d_in[10];
    const float* be1 = (const float*)d_in[11];
    const float* g2  = (const float*)d_in[12];
    const float* be2 = (const float*)d_in[13];

    char* ws = (char*)d_ws;
    u16*  h     = (u16*)(ws + 0);           // 8.39 MB
    u16*  qbuf  = (u16*)(ws + 8388608);     // 8.39 MB
    u16*  Kf    = (u16*)(ws + 16777216);    // 8.39 MB (fragment image)
    u16*  Vf    = (u16*)(ws + 25165824);    // 8.39 MB (fragment image)
    u16*  o     = (u16*)(ws + 33554432);    // 8.39 MB
    float* x1   = (float*)(ws + 41943040);  // 16.78 MB
    u16*  wqkvT = (u16*)(ws + 58720256);    // 6.29 MB
    u16*  wpT   = (u16*)(ws + 65011712);    // 2.10 MB
    u16*  w1T   = (u16*)(ws + 67108864);    // 8.39 MB
    u16*  w2T   = (u16*)(ws + 75497472);    // 8.39 MB -> 80 MB total
    u16*  m     = (u16*)(ws + 0);           // 33.55 MB, aliases h+qbuf+Kf+Vf (dead)
    u16*  h2    = o;                        // aliases o (dead by then)
    float* out  = (float*)d_out;

    prologue_fused<<<16384, 256, 0, stream>>>(Wq, Wk, Wv, Wp, W1, W2,
                                              wqkvT, wpT, w1T, w2T,
                                              x, g1, be1, h);
    gemm_bt<3><<<768, 256, 0, stream>>>(h, wqkvT, 4096, 3072, 1024, nullptr, qbuf, Kf, Vf);
    attn_kernel<<<1024, 256, 0, stream>>>(qbuf, Kf, Vf, o);
    gemm_bt64<<<512, 256, 0, stream>>>(o, wpT, 4096, 1024, 1024, bp, x, x1);
    ln_kernel<<<4096, 256, 0, stream>>>(x1, g2, be2, h2);
    gemm_bt<2><<<1024, 256, 0, stream>>>(h2, w1T, 4096, 4096, 1024, b1, m, nullptr, nullptr);
    gemm_bt64<<<512, 256, 0, stream>>>(m, w2T, 4096, 1024, 4096, b2, x1, out);
}

// Round 25
// 225.328 us; speedup vs baseline: 1.0021x; 1.0021x over previous
//
#include <hip/hip_runtime.h>
#include <hip/hip_bf16.h>
#include <stdint.h>

typedef unsigned short u16;
typedef __attribute__((ext_vector_type(4))) float f32x4;
typedef __attribute__((ext_vector_type(8))) short bf16x8;
typedef __attribute__((ext_vector_type(4))) short bf16x4;
typedef __attribute__((ext_vector_type(4))) unsigned short u16x4;

static __device__ __forceinline__ u16 f2bf(float f) {
    union { float f; unsigned u; } v; v.f = f;
    unsigned r = v.u + 0x7fffu + ((v.u >> 16) & 1u);
    return (u16)(r >> 16);
}

// async global->LDS, 16B per lane; LDS dest = wave-uniform base + lane*16
static __device__ __forceinline__ void gload_lds16(const u16* g, u16* l) {
    __builtin_amdgcn_global_load_lds(
        (const __attribute__((address_space(1))) void*)(uintptr_t)g,
        (__attribute__((address_space(3))) void*)(uint32_t)(uintptr_t)l,
        16, 0, 0);
}

// ---------------- fused prologue: 6 weight transposes + LN1 in ONE launch -------------
// Blocks [0,12288): transpose out[n*K+k] = (bf16) W[k*N+n] per segment:
//   [0,3072): Wq/Wk/Wv (per-head 1024x64); [3072,4096): Wp; [4096,8192): W1;
//   [8192,12288): W2 (4096x1024).
// Blocks [12288,16384): LN1 row (id-12288) of x -> h (bf16).
__global__ __launch_bounds__(256) void prologue_fused(
    const float* __restrict__ Wq, const float* __restrict__ Wk,
    const float* __restrict__ Wv, const float* __restrict__ Wp,
    const float* __restrict__ W1, const float* __restrict__ W2,
    u16* __restrict__ wqkvT, u16* __restrict__ wpT,
    u16* __restrict__ w1T, u16* __restrict__ w2T,
    const float* __restrict__ x, const float* __restrict__ g,
    const float* __restrict__ be, u16* __restrict__ hout)
{
    __shared__ float tile[32][33];
    __shared__ float ps[4], pq[4];
    const int id = blockIdx.x;
    if (id >= 12288) {
        // ---- LN1 row ----
        const int row = id - 12288;
        const int t = threadIdx.x;
        const float4* xr = (const float4*)(x + (size_t)row * 1024);
        float4 v = xr[t];
        float s = v.x + v.y + v.z + v.w;
        float sq = v.x * v.x + v.y * v.y + v.z * v.z + v.w * v.w;
        #pragma unroll
        for (int o = 1; o < 64; o <<= 1) {
            s  += __shfl_xor(s, o);
            sq += __shfl_xor(sq, o);
        }
        if ((t & 63) == 0) { ps[t >> 6] = s; pq[t >> 6] = sq; }
        __syncthreads();
        float S = ps[0] + ps[1] + ps[2] + ps[3];
        float Q = pq[0] + pq[1] + pq[2] + pq[3];
        float mu = S * (1.0f / 1024.0f);
        float var = Q * (1.0f / 1024.0f) - mu * mu;
        float rs = rsqrtf(var + 1e-5f);
        const float4 g4  = ((const float4*)g)[t];
        const float4 be4 = ((const float4*)be)[t];
        u16x4 o4;
        o4[0] = f2bf((v.x - mu) * rs * g4.x + be4.x);
        o4[1] = f2bf((v.y - mu) * rs * g4.y + be4.y);
        o4[2] = f2bf((v.z - mu) * rs * g4.z + be4.z);
        o4[3] = f2bf((v.w - mu) * rs * g4.w + be4.w);
        *(u16x4*)(hout + (size_t)row * 1024 + t * 4) = o4;
        return;
    }
    // ---- weight transpose tile ----
    const float* W; u16* out; int K, N, nt, kt;
    if (id < 3072) {
        const int seg = id >> 10;            // 0:Wq 1:Wk 2:Wv
        const int r = id & 1023;
        const int z = r >> 6;                // head
        const int rem = r & 63;
        W = (seg == 0 ? Wq : (seg == 1 ? Wk : Wv)) + (size_t)z * 65536;
        out = wqkvT + seg * 1048576 + (size_t)z * 65536;
        K = 1024; N = 64;
        nt = (rem & 1) * 32; kt = (rem >> 1) * 32;
    } else if (id < 4096) {
        const int r = id - 3072;
        W = Wp; out = wpT; K = 1024; N = 1024;
        nt = (r & 31) * 32; kt = (r >> 5) * 32;
    } else if (id < 8192) {
        const int r = id - 4096;
        W = W1; out = w1T; K = 1024; N = 4096;
        nt = (r & 127) * 32; kt = (r >> 7) * 32;
    } else {
        const int r = id - 8192;
        W = W2; out = w2T; K = 4096; N = 1024;
        nt = (r & 31) * 32; kt = (r >> 5) * 32;
    }
    const int tx = threadIdx.x & 31, ty = threadIdx.x >> 5;
    #pragma unroll
    for (int i = ty; i < 32; i += 8)
        tile[i][tx] = W[(size_t)(kt + i) * N + nt + tx];
    __syncthreads();
    #pragma unroll
    for (int i = ty; i < 32; i += 8)
        out[(size_t)(nt + i) * K + kt + tx] = f2bf(tile[tx][i]);
}

// ---------------- layernorm: fp32 in -> bf16 out (D = 1024) ---------------
__global__ __launch_bounds__(256) void ln_kernel(
    const float* __restrict__ x, const float* __restrict__ g,
    const float* __restrict__ be, u16* __restrict__ out)
{
    int row = blockIdx.x;
    int t = threadIdx.x;
    const float4* xr = (const float4*)(x + (size_t)row * 1024);
    float4 v = xr[t];
    float s = v.x + v.y + v.z + v.w;
    float sq = v.x * v.x + v.y * v.y + v.z * v.z + v.w * v.w;
    #pragma unroll
    for (int o = 1; o < 64; o <<= 1) {
        s  += __shfl_xor(s, o);
        sq += __shfl_xor(sq, o);
    }
    __shared__ float ps[4], pq[4];
    if ((t & 63) == 0) { ps[t >> 6] = s; pq[t >> 6] = sq; }
    __syncthreads();
    float S = ps[0] + ps[1] + ps[2] + ps[3];
    float Q = pq[0] + pq[1] + pq[2] + pq[3];
    float mu = S * (1.0f / 1024.0f);
    float var = Q * (1.0f / 1024.0f) - mu * mu;
    float rs = rsqrtf(var + 1e-5f);
    const float4 g4  = ((const float4*)g)[t];
    const float4 be4 = ((const float4*)be)[t];
    u16x4 o4;
    o4[0] = f2bf((v.x - mu) * rs * g4.x + be4.x);
    o4[1] = f2bf((v.y - mu) * rs * g4.y + be4.y);
    o4[2] = f2bf((v.z - mu) * rs * g4.z + be4.z);
    o4[3] = f2bf((v.w - mu) * rs * g4.w + be4.w);
    *(u16x4*)(out + (size_t)row * 1024 + t * 4) = o4;
}

// ---------------- GEMM 128x128, BK=64, counted-vmcnt pipelined K-loop (r11) ----------
// XCD-banded 1D grid: XCD k owns M-strips [k*spx, (k+1)*spx), walks N-tiles fast.
template<int EPI>
__global__ __launch_bounds__(256) void gemm_bt(
    const u16* __restrict__ A, const u16* __restrict__ Bt,
    int M, int N, int K,
    const float* __restrict__ bias,
    void* __restrict__ Cout, u16* __restrict__ Kf, u16* __restrict__ Vf)
{
    __shared__ __align__(16) u16 SH[32768];   // 64 KB: 2 bufs x (A 16KB + B 16KB)
    const int bid = blockIdx.x;
    const int xcd = bid & 7, idx = bid >> 3;
    const int nmx = N >> 7;                    // N-tiles
    const int spx = (M >> 7) >> 3;             // M-strips per XCD
    const int tm = (xcd * spx + idx / nmx) * 128;
    const int tn = (idx % nmx) * 128;
    const int t = threadIdx.x;
    const int lane = t & 63, wave = t >> 6;
    const int wr = wave >> 1, wc = wave & 1;
    const int lq = lane & 15, lg = lane >> 4;
    f32x4 acc[4][4] = {};

    const int srow8 = lane >> 3;                       // 0..7
    const int skoff = ((lane & 7) ^ srow8) * 8;        // u16 offset within 64-wide k
    const u16* ag = A  + (size_t)(tm + wave * 32 + srow8) * K + skoff;
    const u16* bg = Bt + (size_t)(tn + wave * 32 + srow8) * K + skoff;

    auto STAGE = [&](int buf, int k0) {
        u16* ab = SH + buf * 16384 + wave * 2048;
        u16* bb = SH + buf * 16384 + 8192 + wave * 2048;
        #pragma unroll
        for (int j = 0; j < 4; ++j) {
            gload_lds16(ag + (size_t)(j * 8) * K + k0, ab + j * 512);
            gload_lds16(bg + (size_t)(j * 8) * K + k0, bb + j * 512);
        }
    };

    const int KT = K >> 6;
    STAGE(0, 0);
    STAGE(1, 64);
    asm volatile("s_waitcnt vmcnt(8)" ::: "memory");
    __builtin_amdgcn_sched_barrier(0);
    __builtin_amdgcn_s_barrier();

    for (int kt = 0; kt < KT; ++kt) {
        const int buf = kt & 1;
        const u16* abuf = SH + buf * 16384;
        const u16* bbuf = abuf + 8192;
        bf16x8 af[4][2], bfv[4][2];
        #pragma unroll
        for (int m = 0; m < 4; ++m) {
            const int row = wr * 64 + m * 16 + lq;
            #pragma unroll
            for (int kk = 0; kk < 2; ++kk) {
                const int slot = (kk * 4 + lg) ^ (row & 7);
                af[m][kk] = *(const bf16x8*)(abuf + row * 64 + slot * 8);
            }
        }
        #pragma unroll
        for (int n = 0; n < 4; ++n) {
            const int col = wc * 64 + n * 16 + lq;
            #pragma unroll
            for (int kk = 0; kk < 2; ++kk) {
                const int slot = (kk * 4 + lg) ^ (col & 7);
                bfv[n][kk] = *(const bf16x8*)(bbuf + col * 64 + slot * 8);
            }
        }
        asm volatile("s_waitcnt lgkmcnt(0)" ::: "memory");
        __builtin_amdgcn_sched_barrier(0);
        __builtin_amdgcn_s_barrier();

        const bool pre = (kt + 2 < KT);
        if (pre) STAGE(buf, (kt + 2) << 6);

        __builtin_amdgcn_s_setprio(1);
        #pragma unroll
        for (int m = 0; m < 4; ++m)
            #pragma unroll
            for (int n = 0; n < 4; ++n)
                #pragma unroll
                for (int kk = 0; kk < 2; ++kk)
                    acc[m][n] = __builtin_amdgcn_mfma_f32_16x16x32_bf16(
                        af[m][kk], bfv[n][kk], acc[m][n], 0, 0, 0);
        __builtin_amdgcn_s_setprio(0);

        if (kt + 1 < KT) {
            if (pre) asm volatile("s_waitcnt vmcnt(8)" ::: "memory");
            else     asm volatile("s_waitcnt vmcnt(0)" ::: "memory");
            __builtin_amdgcn_sched_barrier(0);
            __builtin_amdgcn_s_barrier();
        }
    }

    // ---------------- epilogue: stage into LDS, then coalesced dump ----------------
    if (EPI == 2 || (EPI == 3 && tn < 1024)) {
        __syncthreads();
        #pragma unroll
        for (int n = 0; n < 4; ++n) {
            const int cl = wc * 64 + n * 16 + lq;
            #pragma unroll
            for (int m = 0; m < 4; ++m) {
                const int rl = wr * 64 + m * 16 + lg * 4;
                #pragma unroll
                for (int r = 0; r < 4; ++r) {
                    float v = acc[m][n][r];
                    if (EPI == 2) {
                        float xx = v + bias[tn + cl];
                        v = 0.5f * xx * (1.0f + erff(xx * 0.70710678118654752f));
                    }
                    SH[(rl + r) * 136 + cl] = f2bf(v);
                }
            }
        }
        __syncthreads();
        const int row = t >> 1, half = t & 1;
        const int ncols = (EPI == 2) ? N : 1024;
        const uint4* srow4 = (const uint4*)(SH + row * 136 + half * 64);
        uint4* drow = (uint4*)((u16*)Cout + (size_t)(tm + row) * ncols + tn + half * 64);
        #pragma unroll
        for (int i = 0; i < 8; ++i)
            drow[i] = srow4[i];
    } else if (EPI == 3) {
        __syncthreads();
        const bool isK = (tn < 2048);
        #pragma unroll
        for (int n = 0; n < 4; ++n) {
            const int cl = wc * 64 + n * 16 + lq;
            const int d = cl & 63, hl = cl >> 6;
            #pragma unroll
            for (int m = 0; m < 4; ++m) {
                const int rl0 = wr * 64 + m * 16 + lg * 4;
                #pragma unroll
                for (int r = 0; r < 4; ++r) {
                    const int rl = rl0 + r;
                    const int p = rl & 63, kl = rl >> 6;
                    int off;
                    if (isK)
                        off = ((p >> 4) * 2 + (d >> 5)) * 512 + ((d >> 3) & 3) * 128
                            + (p & 15) * 8 + (d & 7);
                    else
                        off = ((p >> 4) * 4 + (d >> 4)) * 256 + ((p >> 2) & 3) * 64
                            + (d & 15) * 4 + (p & 3);
                    SH[(hl * 2 + kl) * 4096 + off] = f2bf(acc[m][n][r]);
                }
            }
        }
        __syncthreads();
        const int img = t >> 6, ln = t & 63;
        const int hl = img >> 1, kl = img & 1;
        const int hh = ((tn - (isK ? 1024 : 2048)) >> 6) + hl;
        const int bb = tm >> 11, pp = tm & 2047;
        u16* base = (isK ? Kf : Vf) + (size_t)(bb * 16 + hh) * 131072
                  + (size_t)((pp >> 6) + kl) * 4096;
        const u16* simg = SH + img * 4096;
        #pragma unroll
        for (int i = 0; i < 8; ++i)
            *(uint4*)(base + ln * 8 + i * 512) = *(const uint4*)(simg + ln * 8 + i * 512);
    }
}

// ---------------- GEMM 128x64, BK=64, counted-vmcnt pipeline, XCD-banded -------------
__global__ __launch_bounds__(256) void gemm_bt64(
    const u16* __restrict__ A, const u16* __restrict__ Bt,
    int M, int N, int K,
    const float* __restrict__ bias, const float* __restrict__ res,
    float* __restrict__ Cout)
{
    __shared__ __align__(16) u16 SH[24576];   // 48 KB
    const int bid = blockIdx.x;
    const int xcd = bid & 7, idx = bid >> 3;
    const int nmx = N >> 6;                    // N-tiles (64 wide)
    const int spx = (M >> 7) >> 3;             // M-strips per XCD
    const int tm = (xcd * spx + idx / nmx) * 128;
    const int tn = (idx % nmx) * 64;
    const int t = threadIdx.x;
    const int lane = t & 63, wave = t >> 6;
    const int wr = wave >> 1, wc = wave & 1;      // wave tile: 64 rows x 32 cols
    const int lq = lane & 15, lg = lane >> 4;
    f32x4 acc[4][2] = {};

    const int srow8 = lane >> 3;                       // 0..7
    const int skoff = ((lane & 7) ^ srow8) * 8;        // pre-swizzled source slot
    const u16* ag = A  + (size_t)(tm + wave * 32 + srow8) * K + skoff;
    const u16* bg = Bt + (size_t)(tn + wave * 16 + srow8) * K + skoff;

    auto STAGE = [&](int buf, int k0) {
        u16* ab = SH + buf * 12288 + wave * 2048;          // A: [128][64]
        u16* bb = SH + buf * 12288 + 8192 + wave * 1024;   // B: [64][64]
        #pragma unroll
        for (int j = 0; j < 4; ++j)
            gload_lds16(ag + (size_t)(j * 8) * K + k0, ab + j * 512);
        #pragma unroll
        for (int j = 0; j < 2; ++j)
            gload_lds16(bg + (size_t)(j * 8) * K + k0, bb + j * 512);
    };

    const int KT = K >> 6;
    STAGE(0, 0);
    STAGE(1, 64);
    asm volatile("s_waitcnt vmcnt(6)" ::: "memory");
    __builtin_amdgcn_sched_barrier(0);
    __builtin_amdgcn_s_barrier();

    for (int kt = 0; kt < KT; ++kt) {
        const int buf = kt & 1;
        const u16* abuf = SH + buf * 12288;
        const u16* bbuf = abuf + 8192;
        bf16x8 af[4][2], bfr[2][2];
        #pragma unroll
        for (int m = 0; m < 4; ++m) {
            const int row = wr * 64 + m * 16 + lq;
            #pragma unroll
            for (int kk = 0; kk < 2; ++kk) {
                const int slot = (kk * 4 + lg) ^ (row & 7);
                af[m][kk] = *(const bf16x8*)(abuf + row * 64 + slot * 8);
            }
        }
        #pragma unroll
        for (int n = 0; n < 2; ++n) {
            const int col = wc * 32 + n * 16 + lq;
            #pragma unroll
            for (int kk = 0; kk < 2; ++kk) {
                const int slot = (kk * 4 + lg) ^ (col & 7);
                bfr[n][kk] = *(const bf16x8*)(bbuf + col * 64 + slot * 8);
            }
        }
        asm volatile("s_waitcnt lgkmcnt(0)" ::: "memory");
        __builtin_amdgcn_sched_barrier(0);
        __builtin_amdgcn_s_barrier();

        const bool pre = (kt + 2 < KT);
        if (pre) STAGE(buf, (kt + 2) << 6);

        __builtin_amdgcn_s_setprio(1);
        #pragma unroll
        for (int m = 0; m < 4; ++m)
            #pragma unroll
            for (int n = 0; n < 2; ++n)
                #pragma unroll
                for (int kk = 0; kk < 2; ++kk)
                    acc[m][n] = __builtin_amdgcn_mfma_f32_16x16x32_bf16(
                        af[m][kk], bfr[n][kk], acc[m][n], 0, 0, 0);
        __builtin_amdgcn_s_setprio(0);

        if (kt + 1 < KT) {
            if (pre) asm volatile("s_waitcnt vmcnt(6)" ::: "memory");
            else     asm volatile("s_waitcnt vmcnt(0)" ::: "memory");
            __builtin_amdgcn_sched_barrier(0);
            __builtin_amdgcn_s_barrier();
        }
    }

    #pragma unroll
    for (int m = 0; m < 4; ++m)
        #pragma unroll
        for (int n = 0; n < 2; ++n) {
            const int col = tn + wc * 32 + n * 16 + lq;
            #pragma unroll
            for (int r = 0; r < 4; ++r) {
                const int row = tm + wr * 64 + m * 16 + lg * 4 + r;
                Cout[(size_t)row * N + col] = acc[m][n][r] + bias[col] + res[(size_t)row * N + col];
            }
        }
}

// ---------------- causal flash attention: 4 waves/block, LDS-staged K/V --------------
__global__ __launch_bounds__(256, 4) void attn_kernel(
    const u16* __restrict__ qb, const u16* __restrict__ Kf,
    const u16* __restrict__ Vf, u16* __restrict__ o)
{
    const int P = 2048;
    __shared__ __align__(16) u16 KB[2][4096];
    __shared__ __align__(16) u16 VB[2][4096];
    int blk = blockIdx.x;
    int qt = 31 - (blk >> 5);           // 64-row q tiles, heavy first (LPT)
    int bh = blk & 31;
    int h = bh & 15, b = bh >> 4;
    int w = threadIdx.x >> 6, lane = threadIdx.x & 63;
    int lq = lane & 15, lg = lane >> 4;
    int q0 = qt * 64 + w * 16;
    const u16* qptr = qb + (size_t)(b * P + q0 + lq) * 1024 + h * 64 + lg * 8;
    bf16x8 qf0 = *(const bf16x8*)qptr;
    bf16x8 qf1 = *(const bf16x8*)(qptr + 32);
    const u16* Kfb = Kf + (size_t)bh * 131072;
    const u16* Vfb = Vf + (size_t)bh * 131072;
    const float C2 = 0.03125f * 1.44269504f;     // D^-0.5 * log2(e)
    const int moff = w * 16 + lq;                // causal threshold within last block
    float m2 = -1e30f, l_run = 0.f;
    f32x4 accO[4] = {};
    const int nkvb = qt + 1;

    const int vsel = w >> 1, half = w & 1;
    auto STAGE = [&](int buf, int kvb) {
        const u16* src = (vsel ? Vfb : Kfb) + (size_t)kvb * 4096 + half * 2048 + lane * 8;
        u16* dst = (vsel ? &VB[buf][half * 2048] : &KB[buf][half * 2048]);
        #pragma unroll
        for (int i = 0; i < 4; ++i)
            gload_lds16(src + i * 512, dst + i * 512);
    };

    auto COMPUTE = [&](int buf, bool last) {
        const u16* kbase = KB[buf] + lane * 8;
        f32x4 st[4];
        #pragma unroll
        for (int ss = 0; ss < 4; ++ss) {
            bf16x8 kf0 = *(const bf16x8*)(kbase + ss * 1024);
            bf16x8 kf1 = *(const bf16x8*)(kbase + ss * 1024 + 512);
            f32x4 z = {0.f, 0.f, 0.f, 0.f};
            st[ss] = __builtin_amdgcn_mfma_f32_16x16x32_bf16(kf0, qf0, z, 0, 0, 0);
            st[ss] = __builtin_amdgcn_mfma_f32_16x16x32_bf16(kf1, qf1, st[ss], 0, 0, 0);
        }
        float rmax = -1e30f;
        #pragma unroll
        for (int ss = 0; ss < 4; ++ss)
            #pragma unroll
            for (int r = 0; r < 4; ++r) {
                float v = st[ss][r] * C2;
                if (last && (ss * 16 + lg * 4 + r > moff)) v = -1e30f;
                st[ss][r] = v;
                rmax = fmaxf(rmax, v);
            }
        rmax = fmaxf(rmax, __shfl_xor(rmax, 16));
        rmax = fmaxf(rmax, __shfl_xor(rmax, 32));
        if (__any(rmax > m2 + 11.5f)) {            // defer-max (T13)
            float m2n = fmaxf(m2, rmax);
            float alpha = exp2f(m2 - m2n);
            l_run *= alpha;
            #pragma unroll
            for (int r = 0; r < 4; ++r) {
                float ar = __shfl(alpha, lg * 4 + r);
                accO[0][r] *= ar; accO[1][r] *= ar; accO[2][r] *= ar; accO[3][r] *= ar;
            }
            m2 = m2n;
        }
        float psum = 0.f;
        bf16x4 pf[4];
        #pragma unroll
        for (int ss = 0; ss < 4; ++ss)
            #pragma unroll
            for (int r = 0; r < 4; ++r) {
                float pv = exp2f(st[ss][r] - m2);
                psum += pv;
                pf[ss][r] = (short)f2bf(pv);
            }
        psum += __shfl_xor(psum, 16);
        psum += __shfl_xor(psum, 32);
        l_run += psum;
        const u16* vbase = VB[buf] + lane * 4;
        #pragma unroll
        for (int ks = 0; ks < 4; ++ks)
            #pragma unroll
            for (int c = 0; c < 4; ++c) {
                bf16x4 vfr = *(const bf16x4*)(vbase + (ks * 4 + c) * 256);
                accO[c] = __builtin_amdgcn_mfma_f32_16x16x16bf16_1k(pf[ks], vfr, accO[c], 0, 0, 0);
            }
    };

    STAGE(0, 0);
    __syncthreads();
    int cur = 0;
    for (int kvb = 0; kvb < nkvb; ++kvb) {
        if (kvb + 1 < nkvb) STAGE(cur ^ 1, kvb + 1);
        COMPUTE(cur, kvb == nkvb - 1);
        __syncthreads();
        cur ^= 1;
    }

    #pragma unroll
    for (int r = 0; r < 4; ++r) {
        float l_r = __shfl(l_run, lg * 4 + r);
        float inv = 1.0f / l_r;
        size_t orow = (size_t)(b * P + q0 + lg * 4 + r) * 1024 + h * 64;
        #pragma unroll
        for (int c = 0; c < 4; ++c)
            o[orow + c * 16 + lq] = f2bf(accO[c][r] * inv);
    }
}

extern "C" void kernel_launch(void* const* d_in, const int* in_sizes, int n_in,
                              void* d_out, int out_size, void* d_ws, size_t ws_size,
                              hipStream_t stream)
{
    const float* x   = (const float*)d_in[0];
    const float* Wq  = (const float*)d_in[1];
    const float* Wk  = (const float*)d_in[2];
    const float* Wv  = (const float*)d_in[3];
    const float* Wp  = (const float*)d_in[4];
    const float* bp  = (const float*)d_in[5];
    const float* W1  = (const float*)d_in[6];
    const float* b1  = (const float*)d_in[7];
    const float* W2  = (const float*)d_in[8];
    const float* b2  = (const float*)d_in[9];
    const float* g1  = (const float*)d_in[10];
    const float* be1 = (const float*)d_in[11];
    const float* g2  = (const float*)d_in[12];
    const float* be2 = (const float*)d_in[13];

    char* ws = (char*)d_ws;
    u16*  h     = (u16*)(ws + 0);           // 8.39 MB
    u16*  qbuf  = (u16*)(ws + 8388608);     // 8.39 MB
    u16*  Kf    = (u16*)(ws + 16777216);    // 8.39 MB (fragment image)
    u16*  Vf    = (u16*)(ws + 25165824);    // 8.39 MB (fragment image)
    u16*  o     = (u16*)(ws + 33554432);    // 8.39 MB
    float* x1   = (float*)(ws + 41943040);  // 16.78 MB
    u16*  wqkvT = (u16*)(ws + 58720256);    // 6.29 MB
    u16*  wpT   = (u16*)(ws + 65011712);    // 2.10 MB
    u16*  w1T   = (u16*)(ws + 67108864);    // 8.39 MB
    u16*  w2T   = (u16*)(ws + 75497472);    // 8.39 MB -> 80 MB total
    u16*  m     = (u16*)(ws + 0);           // 33.55 MB, aliases h+qbuf+Kf+Vf (dead)
    u16*  h2    = o;                        // aliases o (dead by then)
    float* out  = (float*)d_out;

    prologue_fused<<<16384, 256, 0, stream>>>(Wq, Wk, Wv, Wp, W1, W2,
                                              wqkvT, wpT, w1T, w2T,
                                              x, g1, be1, h);
    gemm_bt<3><<<768, 256, 0, stream>>>(h, wqkvT, 4096, 3072, 1024, nullptr, qbuf, Kf, Vf);
    attn_kernel<<<1024, 256, 0, stream>>>(qbuf, Kf, Vf, o);
    gemm_bt64<<<512, 256, 0, stream>>>(o, wpT, 4096, 1024, 1024, bp, x, x1);
    ln_kernel<<<4096, 256, 0, stream>>>(x1, g2, be2, h2);
    gemm_bt<2><<<1024, 256, 0, stream>>>(h2, w1T, 4096, 4096, 1024, b1, m, nullptr, nullptr);
    gemm_bt64<<<512, 256, 0, stream>>>(m, w2T, 4096, 1024, 4096, b2, x1, out);
}